// Round 4
// baseline (67.477 us; speedup 1.0000x reference)
//
#include <hip/hip_runtime.h>

#define RCR 5.2f
#define RCA 3.5f
#define PI_F 3.14159265358979323846f

// 4 atoms per 256-thread block, one wave per atom (no inter-wave data flow).
// Per wave: lane j computes neighbor-j data; ballot-compacted radial & angular
// lists; radial: lane-per-slot over ~10 compacted neighbors; angular: 2
// pairs/iter, 32 lanes per pair (one (shell,angle) slot each).
__global__ __launch_bounds__(256)
void aev_kernel(const int* __restrict__ species,
                const float* __restrict__ coords,
                float* __restrict__ out)
{
    const int w    = threadIdx.x >> 6;        // wave id 0..3
    const int l    = threadIdx.x & 63;        // lane == neighbor index
    const int atom = blockIdx.x * 4 + w;      // c*64 + i
    const int c    = atom >> 6;
    const int i    = atom & 63;

    __shared__ float cx[4][64], cy[4][64], cz[4][64];
    __shared__ float cd_[4][64], cinv[4][64], cfa[4][64];
    __shared__ int   csp[4][64];
    __shared__ float rd[4][64], rfc[4][64];
    __shared__ int   rsp[4][64];
    __shared__ unsigned short pairab[4][1954];   // worst case 63*62/2 = 1953
    __shared__ float acc[4][320];

    // ---- per-neighbor data in registers ----
    const int gbase = (c * 64 + l) * 3;
    float x = coords[gbase + 0];
    float y = coords[gbase + 1];
    float z = coords[gbase + 2];
    int  sp = species[c * 64 + l];

    for (int t = l; t < 320; t += 64) acc[w][t] = 0.f;

    float xi = __shfl(x, i);
    float yi = __shfl(y, i);
    float zi = __shfl(z, i);

    float rx = xi - x, ry = yi - y, rz = zi - z;
    float d  = sqrtf(rx * rx + ry * ry + rz * rz);
    bool valid  = (l != i) && (sp != -1);
    bool rvalid = valid && (d <= RCR);
    bool avalid = valid && (d <= RCA);

    unsigned long long rmask = __ballot(rvalid);
    unsigned long long amask = __ballot(avalid);
    const int nr = __popcll(rmask);
    const int n  = __popcll(amask);
    const unsigned long long below = (l == 0) ? 0ull : (~0ull >> (64 - l));

    if (rvalid) {
        int pos = __popcll(rmask & below);
        rd[w][pos]  = d;
        rfc[w][pos] = 0.5f * __cosf(PI_F * d * (1.0f / RCR)) + 0.5f;
        rsp[w][pos] = sp;
    }
    if (avalid) {
        int pos = __popcll(amask & below);
        cx[w][pos] = rx; cy[w][pos] = ry; cz[w][pos] = rz;
        cd_[w][pos]  = d;
        cinv[w][pos] = 1.0f / fmaxf(d, 1e-8f);
        cfa[w][pos]  = 0.5f * __cosf(PI_F * d * (1.0f / RCA)) + 0.5f;
        csp[w][pos]  = sp;
    }
    // pair list over compacted angular indices (register-only inputs)
    if (l < n) {
        int a = l;
        int base = a * (n - 1) - (a * (a - 1)) / 2;
        for (int b = a + 1; b < n; ++b)
            pairab[w][base + (b - a - 1)] = (unsigned short)((a << 8) | b);
    }
    __syncthreads();

    // ---- radial: lane l owns slot (species s = l>>4, shell r = l&15) ----
    const int   s   = l >> 4;
    const float shf = 0.9f + 0.26875f * (float)(l & 15);
    float racc = 0.f;
    for (int m = 0; m < nr; ++m) {
        float dd   = rd[w][m] - shf;
        float term = 0.25f * __expf(-16.f * dd * dd) * rfc[w][m];
        racc += (rsp[w][m] == s) ? term : 0.f;
    }

    // ---- angular: 2 pairs per iteration, 32 lanes per pair ----
    const int   sub  = l & 31;                         // aa*8 + z
    const float shfa = 0.9f + 0.65f * (float)(sub >> 3);
    const float shfz = PI_F / 16.f + (PI_F / 8.f) * (float)(sub & 7);
    const float czv  = __cosf(shfz);
    const float szv  = __sinf(shfz);
    const int   np   = (n * (n - 1)) >> 1;
    const int   half = l >> 5;
    for (int p0 = 0; p0 < np; p0 += 2) {
        int p = p0 + half;
        if (p < np) {
            int ab = pairab[w][p];
            int a = ab >> 8, b = ab & 255;
            float dot = cx[w][a] * cx[w][b] + cy[w][a] * cy[w][b] + cz[w][a] * cz[w][b];
            float ca  = 0.95f * dot * cinv[w][a] * cinv[w][b];
            float sa  = sqrtf(fmaxf(0.f, 1.f - ca * ca));
            float dm  = 0.5f * (cd_[w][a] + cd_[w][b]);
            float fprod = 2.f * cfa[w][a] * cfa[w][b];
            int s1 = csp[w][a], s2 = csp[w][b];
            int mn = min(s1, s2), mx = max(s1, s2);
            int pid = ((mn * (7 - mn)) >> 1) + mx;
            float cdz = ca * czv + sa * szv;
            float t = 0.5f + 0.5f * cdz;
            t = t * t; t = t * t; t = t * t; t = t * t; t = t * t;  // ^32
            float u = dm - shfa;
            float val = t * __expf(-8.f * u * u) * fprod;
            atomicAdd(&acc[w][pid * 32 + sub], val);
        }
    }
    __syncthreads();

    // ---- epilogue: 384 floats per atom, coalesced ----
    const long ob = (long)atom * 384;
    out[ob + l] = racc;
    #pragma unroll
    for (int t = 0; t < 5; ++t)
        out[ob + 64 + t * 64 + l] = acc[w][t * 64 + l];
}

extern "C" void kernel_launch(void* const* d_in, const int* in_sizes, int n_in,
                              void* d_out, int out_size, void* d_ws, size_t ws_size,
                              hipStream_t stream) {
    const int* species  = (const int*)d_in[0];
    const float* coords = (const float*)d_in[1];
    float* out          = (float*)d_out;
    aev_kernel<<<dim3(16 * 64 / 4), dim3(256), 0, stream>>>(species, coords, out);
}

// Round 5
// 66.231 us; speedup vs baseline: 1.0188x; 1.0188x over previous
//
#include <hip/hip_runtime.h>

#define RCR 5.2f
#define RCA 3.5f
#define PI_F 3.14159265358979323846f

// One wave (64 threads) per central atom (c,i). 1024 blocks.
// Lane j computes neighbor-j data; ballot-compacted radial & angular lists;
// radial: lane-per-slot over ~10 compacted neighbors;
// angular: 2 pairs/iter, 32 lanes per pair (one (shell,angle) slot each).
__global__ __launch_bounds__(64)
void aev_kernel(const int* __restrict__ species,
                const float* __restrict__ coords,
                float* __restrict__ out)
{
    const int blk = blockIdx.x;     // c*64 + i
    const int c   = blk >> 6;
    const int i   = blk & 63;
    const int l   = threadIdx.x;    // 0..63, lane == neighbor index

    // ---- per-neighbor data in registers ----
    const int gbase = (c * 64 + l) * 3;
    float x = coords[gbase + 0];
    float y = coords[gbase + 1];
    float z = coords[gbase + 2];
    int  sp = species[c * 64 + l];

    float xi = __shfl(x, i);
    float yi = __shfl(y, i);
    float zi = __shfl(z, i);

    float rx = xi - x, ry = yi - y, rz = zi - z;
    float d  = sqrtf(rx * rx + ry * ry + rz * rz);
    bool valid  = (l != i) && (sp != -1);
    bool rvalid = valid && (d <= RCR);
    bool avalid = valid && (d <= RCA);

    __shared__ float cx[64], cy[64], cz[64], cd_[64], cinv[64], cfa[64];
    __shared__ int   csp[64];
    __shared__ float rd[64], rfc[64];
    __shared__ int   rsp[64];
    __shared__ int   pairab[1953];     // worst case 63*62/2
    __shared__ float acc[320];

    for (int t = l; t < 320; t += 64) acc[t] = 0.f;

    unsigned long long rmask = __ballot(rvalid);
    unsigned long long amask = __ballot(avalid);
    const int nr = __popcll(rmask);
    const int n  = __popcll(amask);
    const unsigned long long below = (l == 0) ? 0ull : (~0ull >> (64 - l));

    if (rvalid) {
        int pos = __popcll(rmask & below);
        rd[pos]  = d;
        rfc[pos] = 0.5f * __cosf(PI_F * d * (1.0f / RCR)) + 0.5f;
        rsp[pos] = sp;
    }
    if (avalid) {
        int pos = __popcll(amask & below);
        cx[pos] = rx; cy[pos] = ry; cz[pos] = rz;
        cd_[pos]  = d;
        cinv[pos] = 1.0f / fmaxf(d, 1e-8f);
        cfa[pos]  = 0.5f * __cosf(PI_F * d * (1.0f / RCA)) + 0.5f;
        csp[pos]  = sp;
    }
    // pair list over compacted angular indices (register-only inputs)
    if (l < n) {
        int a = l;
        int base = a * (n - 1) - (a * (a - 1)) / 2;
        for (int b = a + 1; b < n; ++b)
            pairab[base + (b - a - 1)] = (a << 6) | b;
    }
    __syncthreads();

    // ---- radial: lane l owns slot (species s = l>>4, shell r = l&15) ----
    const int   s   = l >> 4;
    const float shf = 0.9f + 0.26875f * (float)(l & 15);
    float racc = 0.f;
    for (int m = 0; m < nr; ++m) {
        float dd   = rd[m] - shf;
        float term = 0.25f * __expf(-16.f * dd * dd) * rfc[m];
        racc += (rsp[m] == s) ? term : 0.f;
    }

    // ---- angular: 2 pairs per iteration, 32 lanes per pair ----
    const int   sub  = l & 31;                         // aa*8 + z
    const float shfa = 0.9f + 0.65f * (float)(sub >> 3);
    const float shfz = PI_F / 16.f + (PI_F / 8.f) * (float)(sub & 7);
    const float czv  = __cosf(shfz);
    const float szv  = __sinf(shfz);
    const int   np   = (n * (n - 1)) >> 1;
    const int   half = l >> 5;
    for (int p0 = 0; p0 < np; p0 += 2) {
        int p = p0 + half;
        if (p < np) {
            int ab = pairab[p];
            int a = ab >> 6, b = ab & 63;
            float dot = cx[a] * cx[b] + cy[a] * cy[b] + cz[a] * cz[b];
            float ca  = 0.95f * dot * cinv[a] * cinv[b];
            float sa  = sqrtf(fmaxf(0.f, 1.f - ca * ca));
            float dm  = 0.5f * (cd_[a] + cd_[b]);
            float fprod = 2.f * cfa[a] * cfa[b];
            int s1 = csp[a], s2 = csp[b];
            int mn = min(s1, s2), mx = max(s1, s2);
            int pid = ((mn * (7 - mn)) >> 1) + mx;
            float cdz = ca * czv + sa * szv;
            float t = 0.5f + 0.5f * cdz;
            t = t * t; t = t * t; t = t * t; t = t * t; t = t * t;  // ^32
            float u = dm - shfa;
            float val = t * __expf(-8.f * u * u) * fprod;
            atomicAdd(&acc[pid * 32 + sub], val);
        }
    }
    __syncthreads();

    // ---- epilogue: 384 floats, coalesced ----
    const long ob = (long)blk * 384;
    out[ob + l] = racc;
    #pragma unroll
    for (int t = 0; t < 5; ++t)
        out[ob + 64 + t * 64 + l] = acc[t * 64 + l];
}

extern "C" void kernel_launch(void* const* d_in, const int* in_sizes, int n_in,
                              void* d_out, int out_size, void* d_ws, size_t ws_size,
                              hipStream_t stream) {
    const int* species  = (const int*)d_in[0];
    const float* coords = (const float*)d_in[1];
    float* out          = (float*)d_out;
    aev_kernel<<<dim3(16 * 64), dim3(64), 0, stream>>>(species, coords, out);
}